// Round 3
// baseline (161.517 us; speedup 1.0000x reference)
//
#include <hip/hip_runtime.h>
#include <math.h>

#define NUM_E   100000
#define HIDDEN  64
#define BATCH   32
#define GAMMA_F 12.0f
#define EMB_RANGE_F 0.21875f                       // (12+2)/64
#define INV_TWO_EMB (1.0f / (2.0f * EMB_RANGE_F))  // rev = r * this = phase/(2pi)
#define NE 8                                       // entities per wave

// Kernel A: re_rot/im_rot for all (b,d) into workspace.
// rot[0..2047] = re_rot[b*64+d], rot[2048..4095] = im_rot[b*64+d]
__global__ void rotate_phase_kernel(const int* __restrict__ facts,
                                    const float* __restrict__ ent,
                                    const float* __restrict__ rel,
                                    float* __restrict__ rot) {
    int p = blockIdx.x * blockDim.x + threadIdx.x;   // 0..2047
    if (p >= BATCH * HIDDEN) return;
    int b = p >> 6;
    int d = p & 63;
    int f0 = facts[b * 3 + 0];
    int f1 = facts[b * 3 + 1];
    float hre = ent[(size_t)f0 * 128 + d];
    float him = ent[(size_t)f0 * 128 + 64 + d];
    float r   = rel[(size_t)f1 * 64 + d];
    float rev = r * INV_TWO_EMB;                 // phase/(2pi)
    float s = __builtin_amdgcn_sinf(rev);
    float c = __builtin_amdgcn_cosf(rev);
    rot[p]                  = hre * c - him * s;
    rot[BATCH * HIDDEN + p] = hre * s + him * c;
}

// Kernel B (R3): lane = (batch, dim-half). Each lane holds its rot slice
// (32 re + 32 im) in VGPRs, loaded ONCE per wave -> zero steady-state LDS.
// (R2 burned ~31 us on the DS pipe re-broadcasting rot 100k times.)
// Entity data: uniform-per-half float4 loads (2 lines/inst on the VMEM pipe),
// each entity row still read exactly once device-wide.
// 100000 entities = 3125 blocks x 4 waves x NE(8) exactly -> no bounds checks.
__global__ __launch_bounds__(256) void rotate_dist_kernel(
        const float* __restrict__ ent,
        const float* __restrict__ rot,
        float* __restrict__ out) {
    const int lane = threadIdx.x & 63;
    const int wv   = threadIdx.x >> 6;           // wave in block, 0..3
    const int b    = lane & 31;                  // batch
    const int h    = lane >> 5;                  // dim half: 0 -> d 0..31, 1 -> d 32..63
    const int gw   = blockIdx.x * 4 + wv;        // global wave id, 0..12499
    const int e0   = gw * NE;

    // rot slice for (b,h): per-lane contiguous 128B, 8+8 float4 -> 64 VGPRs.
    float4 RR[8], RI[8];
    {
        const float4* rr_p = (const float4*)(rot + b * 64 + h * 32);
        const float4* ri_p = (const float4*)(rot + 2048 + b * 64 + h * 32);
#pragma unroll
        for (int c = 0; c < 8; ++c) { RR[c] = rr_p[c]; RI[c] = ri_p[c]; }
    }

#pragma unroll 1
    for (int i = 0; i < NE; ++i) {
        const int e = e0 + i;
        // tr/ti for this lane's half: uniform across the 32 lanes of the half.
        const float4* tp = (const float4*)(ent + (size_t)e * 128 + h * 32);
        const float4* ip = (const float4*)(ent + (size_t)e * 128 + 64 + h * 32);
        float4 T[8], I[8];
#pragma unroll
        for (int c = 0; c < 8; ++c) { T[c] = tp[c]; I[c] = ip[c]; }

        // float4 vector arithmetic -> v_pk_*_f32 packing; sqrt stays scalar.
        float4 a4 = make_float4(0.f, 0.f, 0.f, 0.f);
#pragma unroll
        for (int c = 0; c < 8; ++c) {
            float4 dx, dy, s;
            dx.x = RR[c].x - T[c].x; dx.y = RR[c].y - T[c].y;
            dx.z = RR[c].z - T[c].z; dx.w = RR[c].w - T[c].w;
            dy.x = RI[c].x - I[c].x; dy.y = RI[c].y - I[c].y;
            dy.z = RI[c].z - I[c].z; dy.w = RI[c].w - I[c].w;
            s.x = dx.x * dx.x + dy.x * dy.x;
            s.y = dx.y * dx.y + dy.y * dy.y;
            s.z = dx.z * dx.z + dy.z * dy.z;
            s.w = dx.w * dx.w + dy.w * dy.w;
            a4.x += __builtin_amdgcn_sqrtf(s.x);
            a4.y += __builtin_amdgcn_sqrtf(s.y);
            a4.z += __builtin_amdgcn_sqrtf(s.z);
            a4.w += __builtin_amdgcn_sqrtf(s.w);
        }
        float acc = (a4.x + a4.y) + (a4.z + a4.w);
        acc += __shfl_xor(acc, 32, 64);          // combine the two halves
        if (h == 0)
            out[(size_t)b * NUM_E + e] = GAMMA_F - acc;
    }
}

extern "C" void kernel_launch(void* const* d_in, const int* in_sizes, int n_in,
                              void* d_out, int out_size, void* d_ws, size_t ws_size,
                              hipStream_t stream) {
    const int*   facts = (const int*)d_in[0];
    const float* ent   = (const float*)d_in[1];
    const float* rel   = (const float*)d_in[2];
    float*       out   = (float*)d_out;
    float*       rot   = (float*)d_ws;            // 4096 floats = 16 KB

    rotate_phase_kernel<<<dim3((BATCH * HIDDEN + 255) / 256), dim3(256), 0, stream>>>(
        facts, ent, rel, rot);

    // 3125 blocks x 4 waves x 8 entities = 100000 exactly
    rotate_dist_kernel<<<dim3(NUM_E / (NE * 4)), dim3(256), 0, stream>>>(
        ent, rot, out);
}

// Round 4
// 124.852 us; speedup vs baseline: 1.2937x; 1.2937x over previous
//
#include <hip/hip_runtime.h>
#include <math.h>

#define NUM_E   100000
#define HIDDEN  64
#define BATCH   32
#define GAMMA_F 12.0f
#define EMB_RANGE_F 0.21875f                       // (12+2)/64
#define INV_TWO_EMB (1.0f / (2.0f * EMB_RANGE_F))  // rev = r * this = phase/(2pi)

typedef float v4f __attribute__((ext_vector_type(4)));

// Kernel A: re_rot/im_rot for all (b,d) into workspace.
// rot[0..2047] = re_rot[b*64+d], rot[2048..4095] = im_rot[b*64+d]
__global__ void rotate_phase_kernel(const int* __restrict__ facts,
                                    const float* __restrict__ ent,
                                    const float* __restrict__ rel,
                                    float* __restrict__ rot) {
    int p = blockIdx.x * blockDim.x + threadIdx.x;   // 0..2047
    if (p >= BATCH * HIDDEN) return;
    int b = p >> 6;
    int d = p & 63;
    int f0 = facts[b * 3 + 0];
    int f1 = facts[b * 3 + 1];
    float hre = ent[(size_t)f0 * 128 + d];
    float him = ent[(size_t)f0 * 128 + 64 + d];
    float r   = rel[(size_t)f1 * 64 + d];
    float rev = r * INV_TWO_EMB;                 // phase/(2pi)
    float s = __builtin_amdgcn_sinf(rev);
    float c = __builtin_amdgcn_cosf(rev);
    rot[p]                  = hre * c - him * s;
    rot[BATCH * HIDDEN + p] = hre * s + him * c;
}

// Kernel B (R4): lane = (batch-pair bg, dim-quarter dg).
//  - rot slice (2 batches x 16 dims x {re,im} = 64 floats) lives in VGPRs,
//    loaded ONCE per wave. __launch_bounds__(256,4) grants a 128-VGPR budget
//    so the compiler actually keeps it (R3's 68-VGPR allocation reloaded it).
//  - entity rows staged block-wide into LDS with coalesced float4 loads
//    (R3's uniform global loads were 32-way-redundant latency chains).
//  - per entity per wave: 8 ds_read_b128 (4-addr 16-way broadcast, 2-way
//    bank aliasing max = free) + ~80 packed VALU + 32 sqrt + 4 shfl_xor.
//  - 3125 blocks x 32 entities = 100000 exactly; 4 waves x 8 entities each.
__global__ __launch_bounds__(256, 4) void rotate_dist_kernel(
        const float* __restrict__ ent,
        const float* __restrict__ rot,
        float* __restrict__ out) {
    __shared__ float s_ent[32 * 128];            // 16 KB: 32 entity rows

    const int t     = threadIdx.x;
    const int tile0 = blockIdx.x * 32;           // first entity of this block

    // rot slice -> registers (global loads, independent of staging below)
    const int lane = t & 63;
    const int wv   = t >> 6;                     // wave 0..3
    const int bg   = lane & 15;                  // batch pair: batches 2bg, 2bg+1
    const int dg   = lane >> 4;                  // dim quarter: dims 16dg..16dg+15
    v4f RR[2][4], RI[2][4];
#pragma unroll
    for (int kb = 0; kb < 2; ++kb) {
        const int b = bg * 2 + kb;
        const v4f* pr = (const v4f*)(rot + b * 64 + dg * 16);
        const v4f* pi = (const v4f*)(rot + 2048 + b * 64 + dg * 16);
#pragma unroll
        for (int c = 0; c < 4; ++c) { RR[kb][c] = pr[c]; RI[kb][c] = pi[c]; }
    }

    // stage 32 entity rows (16 KB), fully coalesced: 4 float4 per thread
    {
        const v4f* g4 = (const v4f*)(ent + (size_t)tile0 * 128);
        v4f* s4 = (v4f*)s_ent;
#pragma unroll
        for (int j = 0; j < 4; ++j) s4[t + 256 * j] = g4[t + 256 * j];
    }
    __syncthreads();

#pragma unroll 1
    for (int i = 0; i < 8; ++i) {
        const int e_local = wv * 8 + i;
        const int e       = tile0 + e_local;
        const v4f* pr = (const v4f*)(s_ent + e_local * 128 + dg * 16);
        const v4f* pi = (const v4f*)(s_ent + e_local * 128 + 64 + dg * 16);
        v4f er[4], ei[4];
#pragma unroll
        for (int c = 0; c < 4; ++c) { er[c] = pr[c]; ei[c] = pi[c]; }

        float sum0, sum1;
#pragma unroll
        for (int kb = 0; kb < 2; ++kb) {
            v4f a = (v4f){0.f, 0.f, 0.f, 0.f};
#pragma unroll
            for (int c = 0; c < 4; ++c) {
                v4f dx = RR[kb][c] - er[c];
                v4f dy = RI[kb][c] - ei[c];
                v4f s  = dx * dx + dy * dy;
                a.x += __builtin_amdgcn_sqrtf(s.x);
                a.y += __builtin_amdgcn_sqrtf(s.y);
                a.z += __builtin_amdgcn_sqrtf(s.z);
                a.w += __builtin_amdgcn_sqrtf(s.w);
            }
            float sm = (a.x + a.y) + (a.z + a.w);   // this lane's 16-dim partial
            sm += __shfl_xor(sm, 16, 64);           // combine dim-quarters
            sm += __shfl_xor(sm, 32, 64);
            if (kb == 0) sum0 = sm; else sum1 = sm;
        }
        // lane (bg, dg<2) stores batch 2bg+dg
        if (dg < 2)
            out[(size_t)(bg * 2 + dg) * NUM_E + e] =
                GAMMA_F - (dg == 0 ? sum0 : sum1);
    }
}

extern "C" void kernel_launch(void* const* d_in, const int* in_sizes, int n_in,
                              void* d_out, int out_size, void* d_ws, size_t ws_size,
                              hipStream_t stream) {
    const int*   facts = (const int*)d_in[0];
    const float* ent   = (const float*)d_in[1];
    const float* rel   = (const float*)d_in[2];
    float*       out   = (float*)d_out;
    float*       rot   = (float*)d_ws;            // 4096 floats = 16 KB

    rotate_phase_kernel<<<dim3((BATCH * HIDDEN + 255) / 256), dim3(256), 0, stream>>>(
        facts, ent, rel, rot);

    // 3125 blocks x 32 entities/block = 100000 exactly
    rotate_dist_kernel<<<dim3(NUM_E / 32), dim3(256), 0, stream>>>(
        ent, rot, out);
}

// Round 5
// 123.023 us; speedup vs baseline: 1.3129x; 1.0149x over previous
//
#include <hip/hip_runtime.h>
#include <math.h>

#define NUM_E   100000
#define HIDDEN  64
#define BATCH   32
#define GAMMA_F 12.0f
#define EMB_RANGE_F 0.21875f                       // (12+2)/64
#define INV_TWO_EMB (1.0f / (2.0f * EMB_RANGE_F))  // rev = r * this = phase/(2pi)

typedef float v4f __attribute__((ext_vector_type(4)));

// Kernel A: re_rot/im_rot for all (b,d) into workspace.
// rot[0..2047] = re_rot[b*64+d], rot[2048..4095] = im_rot[b*64+d]
__global__ void rotate_phase_kernel(const int* __restrict__ facts,
                                    const float* __restrict__ ent,
                                    const float* __restrict__ rel,
                                    float* __restrict__ rot) {
    int p = blockIdx.x * blockDim.x + threadIdx.x;   // 0..2047
    if (p >= BATCH * HIDDEN) return;
    int b = p >> 6;
    int d = p & 63;
    int f0 = facts[b * 3 + 0];
    int f1 = facts[b * 3 + 1];
    float hre = ent[(size_t)f0 * 128 + d];
    float him = ent[(size_t)f0 * 128 + 64 + d];
    float r   = rel[(size_t)f1 * 64 + d];
    float rev = r * INV_TWO_EMB;                 // phase/(2pi)
    float s = __builtin_amdgcn_sinf(rev);
    float c = __builtin_amdgcn_cosf(rev);
    rot[p]                  = hre * c - him * s;
    rot[BATCH * HIDDEN + p] = hre * s + him * c;
}

// Kernel B (R5): R4 structure (lane=(batch-pair bg, dim-quarter dg), rot in
// VGPRs, entity tile in LDS) + ILP fixes for the 38% VALU-idle R4 showed:
//  - shuffle reductions DEFERRED to group-of-4 boundaries: 8 independent
//    shfl chains pipelined, instead of 8 serial 2-deep chains (R4's
//    per-entity ~60-cyc DS-latency tail).
//  - entity loop unrolled x2 so the next entity's ds_reads issue under the
//    current entity's sqrt chain.
//  - er/ei loaded per-c (short live ranges) to fit the 128-VGPR budget of
//    __launch_bounds__(256,4).
//  - stores deferred to group end (terminal, never stall the loop).
__global__ __launch_bounds__(256, 4) void rotate_dist_kernel(
        const float* __restrict__ ent,
        const float* __restrict__ rot,
        float* __restrict__ out) {
    __shared__ float s_ent[32 * 128];            // 16 KB: 32 entity rows

    const int t     = threadIdx.x;
    const int tile0 = blockIdx.x * 32;
    const int lane  = t & 63;
    const int wv    = t >> 6;                    // wave 0..3
    const int bg    = lane & 15;                 // batches 2bg, 2bg+1
    const int dg    = lane >> 4;                 // dims 16dg..16dg+15

    // rot slice -> 64 VGPRs, loaded once per wave
    v4f RR[2][4], RI[2][4];
#pragma unroll
    for (int kb = 0; kb < 2; ++kb) {
        const int b = bg * 2 + kb;
        const v4f* pr = (const v4f*)(rot + b * 64 + dg * 16);
        const v4f* pi = (const v4f*)(rot + 2048 + b * 64 + dg * 16);
#pragma unroll
        for (int c = 0; c < 4; ++c) { RR[kb][c] = pr[c]; RI[kb][c] = pi[c]; }
    }

    // stage 32 entity rows, fully coalesced
    {
        const v4f* g4 = (const v4f*)(ent + (size_t)tile0 * 128);
        v4f* s4 = (v4f*)s_ent;
#pragma unroll
        for (int j = 0; j < 4; ++j) s4[t + 256 * j] = g4[t + 256 * j];
    }
    __syncthreads();

#pragma unroll 1
    for (int grp = 0; grp < 2; ++grp) {
        float sm[4][2];

#pragma unroll 2
        for (int i = 0; i < 4; ++i) {
            const int e_local = wv * 8 + grp * 4 + i;
            const v4f* pr = (const v4f*)(s_ent + e_local * 128 + dg * 16);
            const v4f* pi = (const v4f*)(s_ent + e_local * 128 + 64 + dg * 16);

            v4f a0 = (v4f){0.f, 0.f, 0.f, 0.f};
            v4f a1 = (v4f){0.f, 0.f, 0.f, 0.f};
#pragma unroll
            for (int c = 0; c < 4; ++c) {
                const v4f er = pr[c];            // ds_read_b128
                const v4f ei = pi[c];
                // kb = 0
                {
                    v4f dx = RR[0][c] - er;
                    v4f dy = RI[0][c] - ei;
                    v4f sq = dx * dx + dy * dy;  // v_pk_fma-able
                    a0.x += __builtin_amdgcn_sqrtf(sq.x);
                    a0.y += __builtin_amdgcn_sqrtf(sq.y);
                    a0.z += __builtin_amdgcn_sqrtf(sq.z);
                    a0.w += __builtin_amdgcn_sqrtf(sq.w);
                }
                // kb = 1
                {
                    v4f dx = RR[1][c] - er;
                    v4f dy = RI[1][c] - ei;
                    v4f sq = dx * dx + dy * dy;
                    a1.x += __builtin_amdgcn_sqrtf(sq.x);
                    a1.y += __builtin_amdgcn_sqrtf(sq.y);
                    a1.z += __builtin_amdgcn_sqrtf(sq.z);
                    a1.w += __builtin_amdgcn_sqrtf(sq.w);
                }
            }
            sm[i][0] = (a0.x + a0.y) + (a0.z + a0.w);
            sm[i][1] = (a1.x + a1.y) + (a1.z + a1.w);
        }

        // deferred reduction: 8 independent chains, pipelined
#pragma unroll
        for (int i = 0; i < 4; ++i) {
            sm[i][0] += __shfl_xor(sm[i][0], 16, 64);
            sm[i][1] += __shfl_xor(sm[i][1], 16, 64);
        }
#pragma unroll
        for (int i = 0; i < 4; ++i) {
            sm[i][0] += __shfl_xor(sm[i][0], 32, 64);
            sm[i][1] += __shfl_xor(sm[i][1], 32, 64);
        }

        // deferred stores: lane (bg, dg<2) stores batch 2bg+dg
        if (dg < 2) {
            const size_t row = (size_t)(bg * 2 + dg) * NUM_E;
#pragma unroll
            for (int i = 0; i < 4; ++i) {
                const int e = tile0 + wv * 8 + grp * 4 + i;
                const float v = (dg == 0) ? sm[i][0] : sm[i][1];
                out[row + e] = GAMMA_F - v;
            }
        }
    }
}

extern "C" void kernel_launch(void* const* d_in, const int* in_sizes, int n_in,
                              void* d_out, int out_size, void* d_ws, size_t ws_size,
                              hipStream_t stream) {
    const int*   facts = (const int*)d_in[0];
    const float* ent   = (const float*)d_in[1];
    const float* rel   = (const float*)d_in[2];
    float*       out   = (float*)d_out;
    float*       rot   = (float*)d_ws;            // 4096 floats = 16 KB

    rotate_phase_kernel<<<dim3((BATCH * HIDDEN + 255) / 256), dim3(256), 0, stream>>>(
        facts, ent, rel, rot);

    // 3125 blocks x 32 entities/block = 100000 exactly
    rotate_dist_kernel<<<dim3(NUM_E / 32), dim3(256), 0, stream>>>(
        ent, rot, out);
}

// Round 6
// 118.449 us; speedup vs baseline: 1.3636x; 1.0386x over previous
//
#include <hip/hip_runtime.h>
#include <math.h>

#define NUM_E   100000
#define HIDDEN  64
#define BATCH   32
#define GAMMA_F 12.0f
#define EMB_RANGE_F 0.21875f                       // (12+2)/64
#define INV_TWO_EMB (1.0f / (2.0f * EMB_RANGE_F))  // rev = r * this = phase/(2pi)

typedef float v4f __attribute__((ext_vector_type(4)));
typedef float v2f __attribute__((ext_vector_type(2)));

// ---- packed-f32 VALU (VOP3P): 2 dims per instruction ----
static __device__ __forceinline__ v2f pk_sub(v2f a, v2f b) {
    v2f d;
    asm("v_pk_add_f32 %0, %1, %2 neg_lo:[0,1] neg_hi:[0,1]"
        : "=v"(d) : "v"(a), "v"(b));
    return d;
}
static __device__ __forceinline__ v2f pk_mul(v2f a, v2f b) {
    v2f d;
    asm("v_pk_mul_f32 %0, %1, %2" : "=v"(d) : "v"(a), "v"(b));
    return d;
}
static __device__ __forceinline__ v2f pk_fma(v2f a, v2f b, v2f c) {
    v2f d;
    asm("v_pk_fma_f32 %0, %1, %2, %3" : "=v"(d) : "v"(a), "v"(b), "v"(c));
    return d;
}
static __device__ __forceinline__ float sq2(v2f dx, v2f dy) {
    v2f sq = pk_fma(dy, dy, pk_mul(dx, dx));
    return __builtin_amdgcn_sqrtf(sq.x) + __builtin_amdgcn_sqrtf(sq.y);
}
static __device__ __forceinline__ v2f lo2(v4f v) { return __builtin_shufflevector(v, v, 0, 1); }
static __device__ __forceinline__ v2f hi2(v4f v) { return __builtin_shufflevector(v, v, 2, 3); }

// cross-lane add via DPP quad_perm (VALU pipe, not DS)
template <int CTRL>
static __device__ __forceinline__ float dpp_xor_add(float x) {
    int y = __builtin_amdgcn_update_dpp(0, __float_as_int(x), CTRL, 0xF, 0xF, true);
    return x + __int_as_float(y);
}

// Kernel A: re_rot/im_rot for all (b,d) into workspace.
// rot[0..2047] = re_rot[b*64+d], rot[2048..4095] = im_rot[b*64+d]
__global__ void rotate_phase_kernel(const int* __restrict__ facts,
                                    const float* __restrict__ ent,
                                    const float* __restrict__ rel,
                                    float* __restrict__ rot) {
    int p = blockIdx.x * blockDim.x + threadIdx.x;   // 0..2047
    if (p >= BATCH * HIDDEN) return;
    int b = p >> 6;
    int d = p & 63;
    int f0 = facts[b * 3 + 0];
    int f1 = facts[b * 3 + 1];
    float hre = ent[(size_t)f0 * 128 + d];
    float him = ent[(size_t)f0 * 128 + 64 + d];
    float r   = rel[(size_t)f1 * 64 + d];
    float rev = r * INV_TWO_EMB;                 // phase/(2pi)
    float s = __builtin_amdgcn_sinf(rev);
    float c = __builtin_amdgcn_cosf(rev);
    rot[p]                  = hre * c - him * s;
    rot[BATCH * HIDDEN + p] = hre * s + him * c;
}

// Kernel B (R6): lane = (bg in [0,8): batches 4bg..4bg+3, dg in [0,8): dims 8dg..8dg+7).
//  - 4 ds_read_b128/entity (R5 needed 8): halves the DS-read cost.
//  - reduction: xor1/xor2 via DPP quad_perm (VALU) + one ds_swizzle (xor4).
//  - packed f32 (v_pk_*) for the sub/mul/fma chain.
//  - per-wave self-staging of 8 entity rows, NO __syncthreads anywhere.
//  - stores transposed via 132-float LDS scratch: 2 insts / 4 entities,
//    16B-coalesced segments (R5's per-entity stores touched 32 lines each).
__global__ __launch_bounds__(256, 4) void rotate_dist_kernel(
        const float* __restrict__ ent,
        const float* __restrict__ rot,
        float* __restrict__ out) {
    __shared__ float s_ent[4096];       // 4 waves x 8 entity rows (4 KB each)
    __shared__ float s_scr[4][136];     // per-wave transpose scratch (132 used)

    const int t    = threadIdx.x;
    const int lane = t & 63;
    const int wv   = t >> 6;
    const int bg   = lane >> 3;         // batches 4bg..4bg+3
    const int dg   = lane & 7;          // dims 8dg..8dg+7
    const int e0   = blockIdx.x * 32 + wv * 8;

    // rot slice -> 64 VGPRs (4 batches x 8 dims x {re,im}), loaded once
    v2f RR[4][4], RI[4][4];
#pragma unroll
    for (int kb = 0; kb < 4; ++kb) {
        const v4f* pr = (const v4f*)(rot + (bg * 4 + kb) * 64 + dg * 8);
        const v4f* pi = (const v4f*)(rot + 2048 + (bg * 4 + kb) * 64 + dg * 8);
        v4f a = pr[0], b = pr[1], c = pi[0], d = pi[1];
        RR[kb][0] = lo2(a); RR[kb][1] = hi2(a); RR[kb][2] = lo2(b); RR[kb][3] = hi2(b);
        RI[kb][0] = lo2(c); RI[kb][1] = hi2(c); RI[kb][2] = lo2(d); RI[kb][3] = hi2(d);
    }

    // per-wave staging: this wave's 8 entity rows -> its own LDS quarter.
    float* lds = s_ent + wv * 1024;
    {
        const v4f* g4 = (const v4f*)(ent + (size_t)e0 * 128);
        v4f* s4 = (v4f*)lds;
#pragma unroll
        for (int k = 0; k < 4; ++k) s4[k * 64 + lane] = g4[k * 64 + lane];
    }
    // no barrier: the wave consumes only its own writes (lgkmcnt handles dep)

    float* scr = s_scr[wv];

#pragma unroll 1
    for (int grp = 0; grp < 2; ++grp) {
        float p[4][4];                   // [entity in group][batch kb]

#pragma unroll
        for (int i = 0; i < 4; ++i) {
            const float* base = lds + (grp * 4 + i) * 128 + dg * 8;
            v4f er0 = *(const v4f*)(base);
            v4f er1 = *(const v4f*)(base + 4);
            v4f ei0 = *(const v4f*)(base + 64);
            v4f ei1 = *(const v4f*)(base + 68);
            v2f e2[4] = { lo2(er0), hi2(er0), lo2(er1), hi2(er1) };
            v2f i2[4] = { lo2(ei0), hi2(ei0), lo2(ei1), hi2(ei1) };
#pragma unroll
            for (int kb = 0; kb < 4; ++kb) {
                float s0 = sq2(pk_sub(RR[kb][0], e2[0]), pk_sub(RI[kb][0], i2[0]));
                float s1 = sq2(pk_sub(RR[kb][1], e2[1]), pk_sub(RI[kb][1], i2[1]));
                float s2 = sq2(pk_sub(RR[kb][2], e2[2]), pk_sub(RI[kb][2], i2[2]));
                float s3 = sq2(pk_sub(RR[kb][3], e2[3]), pk_sub(RI[kb][3], i2[3]));
                p[i][kb] = (s0 + s1) + (s2 + s3);
            }
        }

        // reduce over dg: xor1,xor2 on VALU (DPP quad_perm), xor4 via shuffle
#pragma unroll
        for (int i = 0; i < 4; ++i)
#pragma unroll
            for (int kb = 0; kb < 4; ++kb) {
                float v = p[i][kb];
                v = dpp_xor_add<0xB1>(v);          // quad_perm [1,0,3,2]
                v = dpp_xor_add<0x4E>(v);          // quad_perm [2,3,0,1]
                v += __shfl_xor(v, 4, 64);
                p[i][kb] = GAMMA_F - v;            // all lanes hold final
            }

        // transpose via per-wave scratch, then coalesced-segment stores
        if (dg < 4) {
#pragma unroll
            for (int i = 0; i < 4; ++i) {
                float val = (dg == 0) ? p[i][0] : (dg == 1) ? p[i][1]
                          : (dg == 2) ? p[i][2] : p[i][3];
                scr[i * 33 + bg * 4 + dg] = val;   // banks distinct per write
            }
        }
#pragma unroll
        for (int j = 0; j < 2; ++j) {
            const int b  = (lane >> 2) + 16 * j;
            const int el = lane & 3;
            float v = scr[el * 33 + b];
            out[(size_t)b * NUM_E + e0 + grp * 4 + el] = v;
        }
    }
}

extern "C" void kernel_launch(void* const* d_in, const int* in_sizes, int n_in,
                              void* d_out, int out_size, void* d_ws, size_t ws_size,
                              hipStream_t stream) {
    const int*   facts = (const int*)d_in[0];
    const float* ent   = (const float*)d_in[1];
    const float* rel   = (const float*)d_in[2];
    float*       out   = (float*)d_out;
    float*       rot   = (float*)d_ws;            // 4096 floats = 16 KB

    rotate_phase_kernel<<<dim3((BATCH * HIDDEN + 255) / 256), dim3(256), 0, stream>>>(
        facts, ent, rel, rot);

    // 3125 blocks x 32 entities/block = 100000 exactly
    rotate_dist_kernel<<<dim3(NUM_E / 32), dim3(256), 0, stream>>>(
        ent, rot, out);
}